// Round 1
// baseline (1184.002 us; speedup 1.0000x reference)
//
#include <hip/hip_runtime.h>
#include <cstdint>
#include <cstddef>

#define S_ROWS 4096
#define DIM 1024
#define NE 64
#define CAP 512
#define NEGV -1e9f

// ---------------- zero-fill d_out (1.07 GB) ----------------
__global__ __launch_bounds__(256) void zerofill(float4* __restrict__ out4, long long n4,
                                                float* __restrict__ out, long long n) {
    long long i = (long long)blockIdx.x * blockDim.x + threadIdx.x;
    long long stride = (long long)gridDim.x * blockDim.x;
    float4 z; z.x = 0.f; z.y = 0.f; z.z = 0.f; z.w = 0.f;
    for (; i < n4; i += stride) out4[i] = z;
    if (blockIdx.x == 0 && threadIdx.x == 0) {
        for (long long j = n4 * 4; j < n; ++j) out[j] = 0.f;
    }
}

// ---------------- logits GEMM: L = X @ W^T  (X [4096,1024], W [64,1024]) ----------------
// grid.x = 64 row-blocks, grid.y = 2 (selects matrix pair). 64x64 C-tile, K-chunk 64.
__global__ __launch_bounds__(256) void gemm64(const float* __restrict__ X1, const float* __restrict__ W1,
                                              const float* __restrict__ X2, const float* __restrict__ W2,
                                              float* __restrict__ L1, float* __restrict__ L2) {
    const float* __restrict__ X = blockIdx.y ? X2 : X1;
    const float* __restrict__ W = blockIdx.y ? W2 : W1;
    float* __restrict__ L = blockIdx.y ? L2 : L1;

    __shared__ float As[64][68];   // As[row][k], stride 68 breaks bank aliasing, keeps 16B align
    __shared__ float Bs[64][68];   // Bs[k][expert]

    const int tid = threadIdx.x;
    const int row0 = blockIdx.x * 64;
    const int tx = tid & 15;       // expert group (4 experts)
    const int ty = tid >> 4;       // row group (4 rows)

    float acc[4][4] = {};

    for (int kk = 0; kk < DIM; kk += 64) {
        __syncthreads();
        // stage A tile (coalesced float4) and W tile (transposed into Bs[k][e])
        #pragma unroll
        for (int p = 0; p < 4; ++p) {
            int r  = (tid >> 4) + p * 16;
            int c4 = (tid & 15) * 4;
            float4 a = *(const float4*)&X[(size_t)(row0 + r) * DIM + kk + c4];
            *(float4*)&As[r][c4] = a;
            float4 w = *(const float4*)&W[(size_t)r * DIM + kk + c4];   // r = expert index
            Bs[c4 + 0][r] = w.x;
            Bs[c4 + 1][r] = w.y;
            Bs[c4 + 2][r] = w.z;
            Bs[c4 + 3][r] = w.w;
        }
        __syncthreads();
        #pragma unroll
        for (int k4 = 0; k4 < 64; k4 += 4) {
            float4 a[4], b[4];
            #pragma unroll
            for (int i = 0; i < 4; ++i) a[i] = *(float4*)&As[ty * 4 + i][k4];
            #pragma unroll
            for (int t = 0; t < 4; ++t) b[t] = *(float4*)&Bs[k4 + t][tx * 4];
            #pragma unroll
            for (int i = 0; i < 4; ++i) {
                acc[i][0] += a[i].x * b[0].x + a[i].y * b[1].x + a[i].z * b[2].x + a[i].w * b[3].x;
                acc[i][1] += a[i].x * b[0].y + a[i].y * b[1].y + a[i].z * b[2].y + a[i].w * b[3].y;
                acc[i][2] += a[i].x * b[0].z + a[i].y * b[1].z + a[i].z * b[2].z + a[i].w * b[3].z;
                acc[i][3] += a[i].x * b[0].w + a[i].y * b[1].w + a[i].z * b[2].w + a[i].w * b[3].w;
            }
        }
    }
    #pragma unroll
    for (int i = 0; i < 4; ++i) {
        float4 v; v.x = acc[i][0]; v.y = acc[i][1]; v.z = acc[i][2]; v.w = acc[i][3];
        *(float4*)&L[(size_t)(row0 + ty * 4 + i) * NE + tx * 4] = v;
    }
}

// ---------------- gating: wave per row; lane = expert ----------------
__global__ __launch_bounds__(256) void gatek(const float* __restrict__ L1, const float* __restrict__ L2,
                                             float* __restrict__ gates, int* __restrict__ eidx,
                                             float* __restrict__ gval) {
    const int wid  = threadIdx.x >> 6;
    const int lane = threadIdx.x & 63;
    const int r = blockIdx.x * 4 + wid;

    float l1 = L1[(size_t)r * NE + lane];
    if (lane == 0) l1 = NEGV;     // group 0 excluded before softmax

    // rank under (value desc, index asc) total order -> top-16 set == jax.lax.top_k set
    int cnt = 0;
    #pragma unroll
    for (int j = 0; j < 64; ++j) {
        float vj = __shfl(l1, j);
        if (vj > l1 || (vj == l1 && j < lane)) ++cnt;
    }
    const bool sel = cnt < 16;

    float l2 = L2[(size_t)r * NE + lane];
    float ml = sel ? l2 : NEGV;

    float m = ml;
    #pragma unroll
    for (int o = 32; o; o >>= 1) m = fmaxf(m, __shfl_xor(m, o));
    float ex = expf(ml - m);      // unselected: expf(~-1e9) underflows to exactly 0
    float sum = ex;
    #pragma unroll
    for (int o = 32; o; o >>= 1) sum += __shfl_xor(sum, o);
    float g = ex / sum;

    gates[(size_t)r * NE + lane] = g;

    // argmax over gates, lowest-index tie-break (associative+commutative -> butterfly OK)
    float bg = g; int bi = lane;
    #pragma unroll
    for (int o = 32; o; o >>= 1) {
        float og = __shfl_xor(bg, o);
        int   oi = __shfl_xor(bi, o);
        if (og > bg || (og == bg && oi < bi)) { bg = og; bi = oi; }
    }
    if (lane == 0) { eidx[r] = bi; gval[r] = bg; }
}

// ---------------- l_aux: block per expert; atomicAdd into d_out[0] ----------------
__global__ __launch_bounds__(256) void lauxk(const float* __restrict__ gates, const int* __restrict__ eidx,
                                             float* __restrict__ out) {
    const int e = blockIdx.x;
    float gs = 0.f; int cnt = 0;
    for (int s = threadIdx.x; s < S_ROWS; s += 256) {
        gs  += gates[(size_t)s * NE + e];
        cnt += (eidx[s] == e);
    }
    __shared__ float sg[4]; __shared__ int sc[4];
    #pragma unroll
    for (int o = 32; o; o >>= 1) { gs += __shfl_down(gs, o); cnt += __shfl_down(cnt, o); }
    const int wid = threadIdx.x >> 6, lane = threadIdx.x & 63;
    if (lane == 0) { sg[wid] = gs; sc[wid] = cnt; }
    __syncthreads();
    if (threadIdx.x == 0) {
        float G = sg[0] + sg[1] + sg[2] + sg[3];
        int   C = sc[0] + sc[1] + sc[2] + sc[3];
        // l_aux = sum_e G_e * C_e / (S*S) * (E*E/num_2nd) = sum_e G_e*C_e / 65536
        atomicAdd(out, G * (float)C * (1.0f / 65536.0f));
    }
}

// ---------------- rank + scatter: block per row ----------------
__global__ __launch_bounds__(256) void scatterk(const int* __restrict__ eidx, const float* __restrict__ gval,
                                                float* __restrict__ out) {
    const int s = blockIdx.x;
    const int my = eidx[s];
    int cnt = 0;
    for (int j = threadIdx.x; j < s; j += 256) cnt += (eidx[j] == my);
    __shared__ int sc[4];
    #pragma unroll
    for (int o = 32; o; o >>= 1) cnt += __shfl_down(cnt, o);
    const int wid = threadIdx.x >> 6, lane = threadIdx.x & 63;
    if (lane == 0) sc[wid] = cnt;
    __syncthreads();
    if (threadIdx.x == 0) {
        int rank = sc[0] + sc[1] + sc[2] + sc[3];   // = locations1_s
        if (rank < CAP) {
            size_t base = 1 + (((size_t)s * NE + my) * CAP + (size_t)rank);
            out[base] = gval[s];                                        // combine
            out[base + (size_t)S_ROWS * NE * CAP] = 1.0f;               // dispatch
        }
    }
}

extern "C" void kernel_launch(void* const* d_in, const int* in_sizes, int n_in,
                              void* d_out, int out_size, void* d_ws, size_t ws_size,
                              hipStream_t stream) {
    const float* in1 = (const float*)d_in[0];
    const float* in2 = (const float*)d_in[1];
    const float* wg1 = (const float*)d_in[2];
    const float* wg2 = (const float*)d_in[3];
    float* out = (float*)d_out;

    float* L1    = (float*)d_ws;                       // [S,64]
    float* L2    = L1 + (size_t)S_ROWS * NE;           // [S,64]
    float* gates = L2 + (size_t)S_ROWS * NE;           // [S,64]
    int*   eidx  = (int*)(gates + (size_t)S_ROWS * NE);// [S]
    float* gv    = (float*)(eidx + S_ROWS);            // [S]

    long long n  = (long long)out_size;
    long long n4 = n >> 2;
    zerofill<<<2048, 256, 0, stream>>>((float4*)out, n4, out, n);

    dim3 g(64, 2);
    gemm64<<<g, 256, 0, stream>>>(in1, wg1, in2, wg2, L1, L2);
    gatek<<<S_ROWS / 4, 256, 0, stream>>>(L1, L2, gates, eidx, gv);
    lauxk<<<NE, 256, 0, stream>>>(gates, eidx, out);
    scatterk<<<S_ROWS, 256, 0, stream>>>(eidx, gv, out);
}